// Round 6
// baseline (543.073 us; speedup 1.0000x reference)
//
#include <hip/hip_runtime.h>
#include <hip/hip_bf16.h>

typedef __attribute__((ext_vector_type(8))) short short8;
typedef __attribute__((ext_vector_type(4))) unsigned short ushort4_t;
typedef __attribute__((ext_vector_type(4))) float f32x4;

#define NSH 4        // shards per destination bucket
#define SCAP 32      // capacity per shard (Poisson lambda<=8 -> P(overflow)~1e-11)

__device__ __forceinline__ unsigned short f2bf(float f) {
  unsigned u = __float_as_uint(f);
  u += 0x7FFFu + ((u >> 16) & 1u);
  return (unsigned short)(u >> 16);
}

// ===========================================================================
// K1: edges -> sharded bucket CSR + AA-source compaction slots (inline).
// cnt/map pre-initialized by hipMemsetAsync (cnt=0, map=-1, ccount=0).
// ===========================================================================
__global__ __launch_bounds__(256) void k_edges(
    const int* __restrict__ ei_ap, const int* __restrict__ ei_pp,
    int* __restrict__ map, int* __restrict__ inv, int* __restrict__ ccount,
    int* __restrict__ cnt_ap, int* __restrict__ cnt_pp,
    int* __restrict__ csr_ap, int* __restrict__ csr_pp,
    int e_ap, int e_pp, int nb_ap, int batch)
{
  int b = blockIdx.x;
  if (b < nb_ap) {
    int e = b * 256 + threadIdx.x;
    if (e < e_ap) {
      int d = ei_ap[e_ap + e];
      if (d < batch) {
        int s = ei_ap[e];
        int sh = e & (NSH - 1);
        int pos = atomicAdd(&cnt_ap[d * NSH + sh], 1);
        if (pos < SCAP) csr_ap[(d * NSH + sh) * SCAP + pos] = s;
        // claim a compact row slot exactly once per distinct source
        if (atomicCAS(&map[s], -1, -2) == -1) {
          int slot = atomicAdd(ccount, 1);
          map[s] = slot;
          inv[slot] = s;
        }
      }
    }
  } else {
    int e = (b - nb_ap) * 256 + threadIdx.x;
    if (e < e_pp) {
      int d = ei_pp[e_pp + e];
      if (d < batch) {
        int sh = e & (NSH - 1);
        int pos = atomicAdd(&cnt_pp[d * NSH + sh], 1);
        if (pos < SCAP) csr_pp[(d * NSH + sh) * SCAP + pos] = ei_pp[e];
      }
    }
  }
}

// ===========================================================================
// K2: 4 GEMMs, grid-sliced.  Operand-swapped MFMA (W as A-operand) ->
// direct ushort4 stores, no transpose LDS, no in-loop barriers.
// W staged once/block: coalesced float4 loads, k-pair-packed ds_write_b32.
// ===========================================================================
struct GemmJob {
  const float* X; const int* inv; const int* rowsp; int M;
  const float* W; const float* bias; unsigned short* Y; int nb;
};

__device__ __forceinline__ void gemm_body(const GemmJob& J, int bid, short8* lwb)
{
  const int tid = threadIdx.x;
  const int rows = J.rowsp ? *J.rowsp : J.M;

  // W staging. lwb[(kt*8+nt)*64 + lane] = W[kt*32+(lane>>4)*8+j][nt*16+(lane&15)]
  // Pack (k, k+1) pairs -> one b32 write (u16 index even since j=k&7 even).
  {
    unsigned* lw32 = (unsigned*)lwb;
#pragma unroll
    for (int p = 0; p < 8; ++p) {
      int slot = p * 256 + tid;        // 0..2047
      int kp   = slot >> 5;            // 0..63 -> k = 2*kp
      int n4   = (slot & 31) * 4;      // 0..124, within one 16-col group
      int k = 2 * kp;
      float4 wa = *(const float4*)(J.W + k * 128 + n4);
      float4 wb = *(const float4*)(J.W + (k + 1) * 128 + n4);
      int frag = (k >> 5) * 8 + (n4 >> 4);
      int lbase = ((k >> 3) & 3) * 16;
      int j = k & 7;                   // even
      const float* fa = (const float*)&wa;
      const float* fb = (const float*)&wb;
#pragma unroll
      for (int q = 0; q < 4; ++q) {
        int lane_ = lbase + ((n4 + q) & 15);
        unsigned pk = (unsigned)f2bf(fa[q]) | ((unsigned)f2bf(fb[q]) << 16);
        lw32[(frag * 64 + lane_) * 4 + (j >> 1)] = pk;
      }
    }
  }

  const int wave = tid >> 6;
  const int lane = tid & 63;
  const int quad = lane >> 4;
  const int l16  = lane & 15;
  __syncthreads();

  for (int tile = bid; tile * 64 < rows; tile += J.nb) {
    int ra = tile * 64 + wave * 16 + l16;   // this lane's X/Y row
    long xrow = -1;
    if (ra < rows) xrow = J.inv ? (long)J.inv[ra] : (long)ra;

    short8 xf[4];   // B operand: B[k = quad*8+j][n = l16] = X[row][k]
#pragma unroll
    for (int kt = 0; kt < 4; ++kt) {
      short8 a = {};
      if (xrow >= 0) {
        const float* p = J.X + xrow * 128 + kt * 32 + quad * 8;
        float4 x0 = ((const float4*)p)[0];
        float4 x1 = ((const float4*)p)[1];
        a[0] = (short)f2bf(x0.x); a[1] = (short)f2bf(x0.y);
        a[2] = (short)f2bf(x0.z); a[3] = (short)f2bf(x0.w);
        a[4] = (short)f2bf(x1.x); a[5] = (short)f2bf(x1.y);
        a[6] = (short)f2bf(x1.z); a[7] = (short)f2bf(x1.w);
      }
      xf[kt] = a;
    }

    f32x4 accs[8];
#pragma unroll
    for (int nt = 0; nt < 8; ++nt) {
      f32x4 acc = {0.f, 0.f, 0.f, 0.f};
#pragma unroll
      for (int kt = 0; kt < 4; ++kt)
        acc = __builtin_amdgcn_mfma_f32_16x16x32_bf16(lwb[(kt * 8 + nt) * 64 + lane], xf[kt], acc, 0, 0, 0);
      accs[nt] = acc;  // D: lane l16 = X row, col = nt*16 + quad*4 + r
    }

    if (ra < rows) {
      unsigned short* yp = J.Y + (long)ra * 128;
#pragma unroll
      for (int nt = 0; nt < 8; ++nt) {
        int col = nt * 16 + quad * 4;
        float4 bv = *(const float4*)(J.bias + col);
        ushort4_t v;
        v[0] = f2bf(accs[nt][0] + bv.x);
        v[1] = f2bf(accs[nt][1] + bv.y);
        v[2] = f2bf(accs[nt][2] + bv.z);
        v[3] = f2bf(accs[nt][3] + bv.w);
        *(ushort4_t*)(yp + col) = v;
      }
    }
  }
}

__global__ __launch_bounds__(256) void k_gemms(
    GemmJob j0, GemmJob j1, GemmJob j2, GemmJob j3)
{
  __shared__ short8 lwb[4 * 8 * 64];   // exactly 32 KB
  int b = blockIdx.x;
  if (b < j0.nb)                      gemm_body(j0, b, lwb);
  else if (b < j0.nb + j1.nb)         gemm_body(j1, b - j0.nb, lwb);
  else if (b < j0.nb + j1.nb + j2.nb) gemm_body(j2, b - j0.nb - j1.nb, lwb);
  else                                gemm_body(j3, b - j0.nb - j1.nb - j2.nb, lwb);
}

// ===========================================================================
// K3: fused per-dst GATv2 (both types, 4 shard-streams) + relu + W_lin head.
// One wave/dst, 2 ch/lane.  map!=null -> AP double indirection (compact rows).
// ===========================================================================
__device__ __forceinline__ void gat_type(
    int dst, int c0, const int* __restrict__ cnt, const int* __restrict__ csr,
    const int* __restrict__ map, const unsigned short* __restrict__ xl,
    const unsigned short* __restrict__ xr, const float* __restrict__ att,
    float& h0, float& h1)
{
  int n[NSH];
  {
    int4 c4 = *(const int4*)(cnt + dst * NSH);
    int v0 = c4.x < SCAP ? c4.x : SCAP;
    int v1 = c4.y < SCAP ? c4.y : SCAP;
    int v2 = c4.z < SCAP ? c4.z : SCAP;
    int v3 = c4.w < SCAP ? c4.w : SCAP;
    n[0] = __builtin_amdgcn_readfirstlane(v0);
    n[1] = __builtin_amdgcn_readfirstlane(v1);
    n[2] = __builtin_amdgcn_readfirstlane(v2);
    n[3] = __builtin_amdgcn_readfirstlane(v3);
  }
  int nmax = n[0];
#pragma unroll
  for (int s = 1; s < NSH; ++s) nmax = n[s] > nmax ? n[s] : nmax;

  unsigned upr = *(const unsigned*)(xr + (long)dst * 128 + c0);
  float xr0 = __uint_as_float(upr << 16);
  float xr1 = __uint_as_float(upr & 0xffff0000u);
  float2 at = *(const float2*)(att + c0);

  const int base = dst * (NSH * SCAP);
  float l = 0.f, o0 = 0.f, o1 = 0.f;

  for (int t = 0; t < nmax; ++t) {
    unsigned u[NSH];
#pragma unroll
    for (int s = 0; s < NSH; ++s) {
      if (t < n[s]) {
        int src = csr[base + s * SCAP + t];
        if (map) src = map[src];
        u[s] = *(const unsigned*)(xl + (long)src * 128 + c0);
      }
    }
    float p[NSH], a0[NSH], a1[NSH];
#pragma unroll
    for (int s = 0; s < NSH; ++s) {
      if (t < n[s]) {
        float v0 = __uint_as_float(u[s] << 16);
        float v1 = __uint_as_float(u[s] & 0xffff0000u);
        a0[s] = v0; a1[s] = v1;
        float e0 = v0 + xr0; e0 = e0 > 0.f ? e0 : 0.2f * e0;
        float e1 = v1 + xr1; e1 = e1 > 0.f ? e1 : 0.2f * e1;
        p[s] = at.x * e0 + at.y * e1;
      }
    }
#pragma unroll
    for (int off = 32; off; off >>= 1) {
#pragma unroll
      for (int s = 0; s < NSH; ++s)
        if (t < n[s]) p[s] += __shfl_xor(p[s], off, 64);
    }
#pragma unroll
    for (int s = 0; s < NSH; ++s) {
      if (t < n[s]) {
        float w = __expf(p[s]);
        l += w;
        o0 = fmaf(w, a0[s], o0);
        o1 = fmaf(w, a1[s], o1);
      }
    }
  }
  float invl = (l > 0.f) ? 1.f / l : 0.f;
  h0 = fmaf(o0, invl, h0);
  h1 = fmaf(o1, invl, h1);
}

__global__ __launch_bounds__(256) void k_gat_final(
    const int* __restrict__ cnt_ap, const int* __restrict__ csr_ap,
    const int* __restrict__ map, const unsigned short* __restrict__ xl_aa,
    const unsigned short* __restrict__ xr_ap, const float* __restrict__ att_ap,
    const int* __restrict__ cnt_pp, const int* __restrict__ csr_pp,
    const unsigned short* __restrict__ xl_pp,
    const unsigned short* __restrict__ xr_pp, const float* __restrict__ att_pp,
    const float* __restrict__ bias_ap, const float* __restrict__ bias_pp,
    const float* __restrict__ W_lin, const float* __restrict__ b_lin,
    float* __restrict__ out, int batch)
{
  __shared__ unsigned lw2[64 * 64];  // 16 KB: [cpair][ocol] packed bf16x2
  __shared__ float lh[4][128];       // 2 KB
  for (int e = threadIdx.x; e < 4096; e += 256) {
    int cp = e >> 6, o = e & 63;
    unsigned lo = f2bf(W_lin[(2 * cp) * 64 + o]);
    unsigned hi = f2bf(W_lin[(2 * cp + 1) * 64 + o]);
    lw2[e] = lo | (hi << 16);
  }

  const int wave = threadIdx.x >> 6;
  const int lane = threadIdx.x & 63;
  const int dst = blockIdx.x * 4 + wave;
  const int c0 = 2 * lane;

  float h0 = 0.f, h1 = 0.f;
  if (dst < batch) {
    h0 = bias_ap[c0] + bias_pp[c0];
    h1 = bias_ap[c0 + 1] + bias_pp[c0 + 1];
    gat_type(dst, c0, cnt_ap, csr_ap, map,     xl_aa, xr_ap, att_ap, h0, h1);
    gat_type(dst, c0, cnt_pp, csr_pp, nullptr, xl_pp, xr_pp, att_pp, h0, h1);
  }

  lh[wave][c0]     = h0 > 0.f ? h0 : 0.f;
  lh[wave][c0 + 1] = h1 > 0.f ? h1 : 0.f;
  __syncthreads();

  if (dst < batch) {
    float acc = b_lin[lane];
#pragma unroll 16
    for (int cp = 0; cp < 64; ++cp) {
      unsigned u = lw2[cp * 64 + lane];
      acc = fmaf(lh[wave][2 * cp],     __uint_as_float(u << 16),         acc);
      acc = fmaf(lh[wave][2 * cp + 1], __uint_as_float(u & 0xffff0000u), acc);
    }
    out[(long)dst * 64 + lane] = acc;
  }
}

// ===========================================================================
extern "C" void kernel_launch(void* const* d_in, const int* in_sizes, int n_in,
                              void* d_out, int out_size, void* d_ws, size_t ws_size,
                              hipStream_t stream)
{
  const float* x_aa   = (const float*)d_in[0];
  const float* x_prot = (const float*)d_in[1];
  const int*   ei_ap  = (const int*)d_in[2];
  const int*   ei_pp  = (const int*)d_in[3];
  const float* Wl_ap  = (const float*)d_in[5];
  const float* bl_ap  = (const float*)d_in[6];
  const float* Wr_ap  = (const float*)d_in[7];
  const float* br_ap  = (const float*)d_in[8];
  const float* att_ap = (const float*)d_in[9];
  const float* bias_ap= (const float*)d_in[10];
  const float* Wl_pp  = (const float*)d_in[11];
  const float* bl_pp  = (const float*)d_in[12];
  const float* Wr_pp  = (const float*)d_in[13];
  const float* br_pp  = (const float*)d_in[14];
  const float* att_pp = (const float*)d_in[15];
  const float* bias_pp= (const float*)d_in[16];
  const float* W_lin  = (const float*)d_in[17];
  const float* b_lin  = (const float*)d_in[18];
  float* out = (float*)d_out;

  const int D = 128;
  const int n_aa   = in_sizes[0] / D;
  const int n_prot = in_sizes[1] / D;
  const int e_ap   = in_sizes[2] / 2;
  const int e_pp   = in_sizes[3] / 2;
  const int batch  = out_size / 64;   // 16384

  char* p = (char*)d_ws;
  auto take = [&](size_t n) { char* r = p; p += (n + 255) & ~(size_t)255; return r; };
  unsigned short* xlc_aa = (unsigned short*)take((size_t)n_aa * D * 2);
  unsigned short* xl_pp  = (unsigned short*)take((size_t)n_prot * D * 2);
  unsigned short* xr_ap  = (unsigned short*)take((size_t)batch * D * 2);
  unsigned short* xr_pp  = (unsigned short*)take((size_t)batch * D * 2);
  // contiguous zero-init region: cnt_ap, cnt_pp, ccount
  char* zreg   = take((size_t)batch * NSH * 4 * 2 + 256);
  int* cnt_ap  = (int*)zreg;
  int* cnt_pp  = cnt_ap + (size_t)batch * NSH;
  int* ccount  = cnt_pp + (size_t)batch * NSH;
  int* map     = (int*)take((size_t)n_aa * 4);
  int* inv     = (int*)take((size_t)n_aa * 4);
  int* csr_ap  = (int*)take((size_t)batch * NSH * SCAP * 4);
  int* csr_pp  = (int*)take((size_t)batch * NSH * SCAP * 4);
  (void)ws_size; (void)n_in;

  // init via driver fills (cheaper than a kernel): cnt=0, ccount=0, map=-1
  hipMemsetAsync(zreg, 0, (size_t)batch * NSH * 4 * 2 + 4, stream);
  hipMemsetAsync(map, 0xFF, (size_t)n_aa * 4, stream);

  const int nb_ap = (e_ap + 255) / 256;
  const int nb_pp = (e_pp + 255) / 256;

  k_edges<<<nb_ap + nb_pp, 256, 0, stream>>>(
      ei_ap, ei_pp, map, inv, ccount, cnt_ap, cnt_pp, csr_ap, csr_pp,
      e_ap, e_pp, nb_ap, batch);

  GemmJob j0{x_aa,   inv,     ccount,  0,      Wl_ap, bl_ap, xlc_aa, 512};
  GemmJob j1{x_prot, nullptr, nullptr, n_prot, Wl_pp, bl_pp, xl_pp,  224};
  GemmJob j2{x_prot, nullptr, nullptr, batch,  Wr_ap, br_ap, xr_ap,  144};
  GemmJob j3{x_prot, nullptr, nullptr, batch,  Wr_pp, br_pp, xr_pp,  144};
  k_gemms<<<j0.nb + j1.nb + j2.nb + j3.nb, 256, 0, stream>>>(j0, j1, j2, j3);

  k_gat_final<<<(batch + 3) / 4, 256, 0, stream>>>(
      cnt_ap, csr_ap, map, xlc_aa, xr_ap, att_ap,
      cnt_pp, csr_pp, xl_pp, xr_pp, att_pp,
      bias_ap, bias_pp, W_lin, b_lin, out, batch);
}